// Round 3
// baseline (40.321 us; speedup 1.0000x reference)
//
#include <hip/hip_runtime.h>
#include <math.h>

// Problem constants (match reference)
constexpr int   T_DIM = 4096;
constexpr int   NC    = 10;
constexpr int   CHUNK = 1024;            // columns per block
constexpr int   NCH   = T_DIM / CHUNK;   // 4 chunks per row
constexpr int   NTHR  = CHUNK / 4;       // 256 threads, 4 cols (float4) each
constexpr int   NWAVE = NTHR / 64;       // 4 waves

constexpr float EPS_C   = 0.2f;
constexpr float ALPHA_C = 0.5f;
constexpr float GAMMA_C = 1e-4f;
constexpr float MU_C    = 8e-4f;

// ---------------------------------------------------------------------------
// ws layout (floats):
//   Smean [B*T]  | Amean [B*T] | cmax [B*NCH] | cmin [B*NCH]
//   P1 [B*NCH*8] | P2 [B*NCH*4] | counter (1 uint)
// ---------------------------------------------------------------------------

__global__ __launch_bounds__(NTHR) void mbs_k1(
    const float* __restrict__ scores,
    const float* __restrict__ attw,
    const int*   __restrict__ seqlen,
    float*       __restrict__ ws,
    int B)
{
    float* Smean = ws;
    float* Amean = ws + (size_t)B * T_DIM;
    float* cmax  = Amean + (size_t)B * T_DIM;
    float* cmin  = cmax + (size_t)B * NCH;
    float* P1    = cmin + (size_t)B * NCH;
    unsigned int* cnt =
        (unsigned int*)(P1 + (size_t)B * NCH * 8 + (size_t)B * NCH * 4);

    const int bid  = blockIdx.x;
    const int row  = bid / NCH;
    const int ch   = bid - row * NCH;
    const int tid  = threadIdx.x;
    const int lane = tid & 63;
    const int wid  = tid >> 6;

    if (bid == 0 && tid == 0) *cnt = 0u;   // reset for K2 (poison-safe)

    const int  slen   = seqlen[row];
    const bool pos    = row < (B >> 1);
    const bool isLG   = (row == (B >> 1) - 1) || (row == B - 1);
    const int  t0     = ch * CHUNK + tid * 4;
    const bool active = t0 < slen;

    // ---- channel mean (the only reader of the 42 MB inputs) ----
    float4 s4 = make_float4(0.f, 0.f, 0.f, 0.f);
    float4 a4 = make_float4(0.f, 0.f, 0.f, 0.f);
    if (active) {
        const size_t base = (size_t)row * NC * T_DIM + t0;
#pragma unroll
        for (int c = 0; c < NC; ++c) {
            const float4 sv = *reinterpret_cast<const float4*>(scores + base + (size_t)c * T_DIM);
            const float4 av = *reinterpret_cast<const float4*>(attw   + base + (size_t)c * T_DIM);
            s4.x += sv.x; s4.y += sv.y; s4.z += sv.z; s4.w += sv.w;
            a4.x += av.x; a4.y += av.y; a4.z += av.z; a4.w += av.w;
        }
        const float invNC = 1.0f / (float)NC;
        s4.x *= invNC; s4.y *= invNC; s4.z *= invNC; s4.w *= invNC;
        a4.x *= invNC; a4.y *= invNC; a4.z *= invNC; a4.w *= invNC;
        *reinterpret_cast<float4*>(Smean + (size_t)row * T_DIM + t0) = s4;
        *reinterpret_cast<float4*>(Amean + (size_t)row * T_DIM + t0) = a4;
    }

    const float sarr[4] = {s4.x, s4.y, s4.z, s4.w};
    const float aarr[4] = {a4.x, a4.y, a4.z, a4.w};

    // ---- theta-independent partials + masked max/min ----
    float mx = -INFINITY, mn = INFINITY;
    float v0 = 0.f, v1 = 0.f, v4 = 0.f, v5 = 0.f, v7 = 0.f;
    if (active) {
#pragma unroll
        for (int j = 0; j < 4; ++j) {
            const int t = t0 + j;
            if (t < slen) {
                const float s  = sarr[j];
                const float a  = aarr[j];
                const float sa = s * a;
                mx = fmaxf(mx, a);
                mn = fminf(mn, a);
                if (pos) {
                    v0 += fmaxf(__logf(s),  -100.0f);
                    v1 += fmaxf(__logf(sa), -100.0f);
                    v4 += fabsf(a);
                    if (isLG) v5 += (a - s) * (a - s);
                } else {
                    v0 += fmaxf(__logf(1.0f - s),  -100.0f);
                    v1 += fmaxf(__logf(1.0f - sa), -100.0f);
                    if (isLG) v5 += a * a;
                }
                v7 += s + sa;
            }
        }
    }

    // ---- block reduce (7 values over 4 waves) ----
    float vals[7] = {mx, mn, v0, v1, v4, v5, v7};
#pragma unroll
    for (int off = 32; off; off >>= 1) {
        vals[0] = fmaxf(vals[0], __shfl_down(vals[0], off, 64));
        vals[1] = fminf(vals[1], __shfl_down(vals[1], off, 64));
#pragma unroll
        for (int k = 2; k < 7; ++k)
            vals[k] += __shfl_down(vals[k], off, 64);
    }
    __shared__ float red[NWAVE][7];
    if (lane == 0)
#pragma unroll
        for (int k = 0; k < 7; ++k) red[wid][k] = vals[k];
    __syncthreads();

    if (tid == 0) {
        float tmx = red[0][0], tmn = red[0][1];
        float t2 = red[0][2], t3 = red[0][3], t4 = red[0][4],
              t5 = red[0][5], t6 = red[0][6];
#pragma unroll
        for (int w = 1; w < NWAVE; ++w) {
            tmx = fmaxf(tmx, red[w][0]);
            tmn = fminf(tmn, red[w][1]);
            t2 += red[w][2]; t3 += red[w][3]; t4 += red[w][4];
            t5 += red[w][5]; t6 += red[w][6];
        }
        cmax[(size_t)row * NCH + ch] = tmx;
        cmin[(size_t)row * NCH + ch] = tmn;

        const float inv_slen = 1.0f / (float)slen;
        const float invB2    = 2.0f / (float)B;   // 1/128
        float* p = P1 + (size_t)bid * 8;
        p[0] = ALPHA_C * (-t2 * inv_slen) * invB2;
        p[1] = ALPHA_C * (-t3 * inv_slen) * invB2;
        p[2] = pos ? (GAMMA_C * t4 * invB2) : 0.0f;
        p[3] = (row == B - 1)        ? t5 * inv_slen : 0.0f;  // LG_0
        p[4] = (row == (B >> 1) - 1) ? t5 * inv_slen : 0.0f;  // LG_1
        p[5] = t6 * invB2;
    }
}

__global__ __launch_bounds__(NTHR) void mbs_k2(
    const int* __restrict__ seqlen,
    float*     __restrict__ ws,
    float*     __restrict__ out,
    int B)
{
    float* Smean = ws;
    float* Amean = ws + (size_t)B * T_DIM;
    float* cmax  = Amean + (size_t)B * T_DIM;
    float* cmin  = cmax + (size_t)B * NCH;
    float* P1    = cmin + (size_t)B * NCH;
    float* P2    = P1 + (size_t)B * NCH * 8;
    unsigned int* cnt = (unsigned int*)(P2 + (size_t)B * NCH * 4);

    const int bid  = blockIdx.x;
    const int grid = gridDim.x;
    const int row  = bid / NCH;
    const int ch   = bid - row * NCH;
    const int tid  = threadIdx.x;
    const int lane = tid & 63;
    const int wid  = tid >> 6;

    const int  slen   = seqlen[row];
    const bool pos    = row < (B >> 1);
    const int  t0     = ch * CHUNK + tid * 4;
    const bool active = t0 < slen;

    // ---- per-row theta from chunk partials (dup work per block, cheap) ----
    float mx = -INFINITY, mn = INFINITY;
#pragma unroll
    for (int c = 0; c < NCH; ++c) {
        mx = fmaxf(mx, cmax[(size_t)row * NCH + c]);
        mn = fminf(mn, cmin[(size_t)row * NCH + c]);
    }
    const float theta = (mx - mn) * EPS_C + mn;

    // ---- sup-BCE + smoothness from cached means ----
    float v2 = 0.f, v3 = 0.f, v6 = 0.f;
    if (active) {
        const float4 s4 = *reinterpret_cast<const float4*>(Smean + (size_t)row * T_DIM + t0);
        const float4 a4 = *reinterpret_cast<const float4*>(Amean + (size_t)row * T_DIM + t0);
        const float sarr[4] = {s4.x, s4.y, s4.z, s4.w};
        const float aarr[4] = {a4.x, a4.y, a4.z, a4.w};
#pragma unroll
        for (int j = 0; j < 4; ++j) {
            const int t = t0 + j;
            const float s  = sarr[j];
            const float a  = aarr[j];
            const float sa = s * a;
            if (t < slen) {
                const bool sup = a < theta;
                if (pos) {
                    v2 += sup ? fmaxf(__logf(s),  -100.0f) : -100.0f;
                    v3 += sup ? fmaxf(__logf(sa), -100.0f) : -100.0f;
                } else if (sup) {
                    v2 += fmaxf(__logf(1.0f - s),  -100.0f);
                    v3 += fmaxf(__logf(1.0f - sa), -100.0f);
                }
            }
            if (t < slen - 1) {
                float s2, a2;
                if (j < 3) { s2 = sarr[j + 1]; a2 = aarr[j + 1]; }
                else {
                    s2 = Smean[(size_t)row * T_DIM + t + 1];
                    a2 = Amean[(size_t)row * T_DIM + t + 1];
                }
                const float ds  = s  - s2;
                const float dsa = sa - s2 * a2;
                v6 += ds * ds + dsa * dsa;
            }
        }
    }

    float vals[3] = {v2, v3, v6};
#pragma unroll
    for (int off = 32; off; off >>= 1)
#pragma unroll
        for (int k = 0; k < 3; ++k)
            vals[k] += __shfl_down(vals[k], off, 64);

    __shared__ float red[NWAVE][3];
    __shared__ int   sdone;
    if (lane == 0)
#pragma unroll
        for (int k = 0; k < 3; ++k) red[wid][k] = vals[k];
    __syncthreads();

    if (tid == 0) {
        float t2 = red[0][0], t3 = red[0][1], t6 = red[0][2];
#pragma unroll
        for (int w = 1; w < NWAVE; ++w) {
            t2 += red[w][0]; t3 += red[w][1]; t6 += red[w][2];
        }
        const float inv_slen = 1.0f / (float)slen;
        const float invB2    = 2.0f / (float)B;
        float* p = P2 + (size_t)bid * 4;
        p[0] = (1.0f - ALPHA_C) * (-t2 * inv_slen) * invB2;
        p[1] = (1.0f - ALPHA_C) * (-t3 * inv_slen) * invB2;
        p[2] = MU_C * t6 * invB2;
        __threadfence();
        const unsigned int old = atomicAdd(cnt, 1u);
        sdone = (old == (unsigned int)(grid - 1)) ? 1 : 0;
    }
    __syncthreads();

    // ---- last-block final reduce ----
    if (sdone) {
        __threadfence();   // acquire: see all blocks' partials
        float acc[9];
#pragma unroll
        for (int k = 0; k < 9; ++k) acc[k] = 0.f;
        for (int i = tid; i < grid; i += NTHR) {
            const float* p1 = P1 + (size_t)i * 8;
            const float* p2 = P2 + (size_t)i * 4;
            acc[0] += p1[0]; acc[1] += p1[1];
            acc[2] += p2[0]; acc[3] += p2[1];
            acc[4] += p1[2]; acc[5] += p1[3];
            acc[6] += p1[4]; acc[7] += p2[2];
            acc[8] += p1[5];
        }
#pragma unroll
        for (int off = 32; off; off >>= 1)
#pragma unroll
            for (int k = 0; k < 9; ++k)
                acc[k] += __shfl_down(acc[k], off, 64);
        __shared__ float redf[NWAVE][9];
        if (lane == 0)
#pragma unroll
            for (int k = 0; k < 9; ++k) redf[wid][k] = acc[k];
        __syncthreads();
        if (tid == 0) {
#pragma unroll
            for (int k = 0; k < 9; ++k) {
                float s = redf[0][k];
#pragma unroll
                for (int w = 1; w < NWAVE; ++w) s += redf[w][k];
                out[k] = s;
            }
        }
    }
}

extern "C" void kernel_launch(void* const* d_in, const int* in_sizes, int n_in,
                              void* d_out, int out_size, void* d_ws, size_t ws_size,
                              hipStream_t stream) {
    const float* scores = (const float*)d_in[0];
    const float* attw   = (const float*)d_in[1];
    // d_in[2] = label (unused: reference splits by fixed B/2)
    const int*   seqlen = (const int*)d_in[3];
    const int B = in_sizes[2];
    const int grid = B * NCH;

    mbs_k1<<<dim3(grid), dim3(NTHR), 0, stream>>>(scores, attw, seqlen,
                                                  (float*)d_ws, B);
    mbs_k2<<<dim3(grid), dim3(NTHR), 0, stream>>>(seqlen, (float*)d_ws,
                                                  (float*)d_out, B);
}